// Round 1
// baseline (1659.352 us; speedup 1.0000x reference)
//
#include <hip/hip_runtime.h>

// ---------------- problem constants ----------------
#define S_LEN 2048
#define DIMC  4096
#define NH    32
#define NKV   8
#define HD    128
#define BATCH 2
#define M_TOT (BATCH*S_LEN)          // 4096 rows of x
#define N_QKV (DIMC + 2*NKV*HD)      // 6144 = 4096 q + 1024 k + 1024 v

typedef unsigned short u16;
typedef __attribute__((ext_vector_type(8))) short  short8;  // 8 bf16 (4 VGPRs)
typedef __attribute__((ext_vector_type(4))) float  f32x4;
typedef __attribute__((ext_vector_type(4))) float  fvec4;
typedef __attribute__((ext_vector_type(4))) unsigned short u16x4;

__device__ __forceinline__ u16 f2bf(float f) {
    union { float f; unsigned u; } v; v.f = f;
    unsigned r = v.u + 0x7FFFu + ((v.u >> 16) & 1u);   // RNE
    return (u16)(r >> 16);
}
__device__ __forceinline__ float bf2f(u16 h) {
    union { unsigned u; float f; } v; v.u = ((unsigned)h) << 16;
    return v.f;
}

// async global->LDS, 16B per lane; LDS dest = wave-uniform base + lane*16
__device__ __forceinline__ void gload_lds16(const void* g, void* l) {
    __builtin_amdgcn_global_load_lds(
        (const __attribute__((address_space(1))) void*)g,
        (__attribute__((address_space(3))) void*)l, 16, 0, 0);
}

// ---------------- stage 0: convert / transpose ----------------
__global__ void cvt_f32_bf16(const float* __restrict__ in, u16* __restrict__ out, int n4) {
    int i = blockIdx.x * 256 + threadIdx.x;
    if (i >= n4) return;
    fvec4 v = ((const fvec4*)in)[i];
    u16x4 o;
    o[0] = f2bf(v[0]); o[1] = f2bf(v[1]); o[2] = f2bf(v[2]); o[3] = f2bf(v[3]);
    ((u16x4*)out)[i] = o;
}

// out[n][k] = (bf16) in[k][n];  in is K x N f32
__global__ void transpose_cvt(const float* __restrict__ in, u16* __restrict__ out,
                              int K, int N) {
    __shared__ float tile[32][33];
    int k0 = blockIdx.y * 32, n0 = blockIdx.x * 32;
    int t = threadIdx.x;
    int r = t >> 3, c4 = (t & 7) * 4;
    fvec4 v = *(const fvec4*)&in[(size_t)(k0 + r) * N + n0 + c4];
    tile[r][c4 + 0] = v[0]; tile[r][c4 + 1] = v[1];
    tile[r][c4 + 2] = v[2]; tile[r][c4 + 3] = v[3];
    __syncthreads();
    u16x4 o;
    o[0] = f2bf(tile[c4 + 0][r]); o[1] = f2bf(tile[c4 + 1][r]);
    o[2] = f2bf(tile[c4 + 2][r]); o[3] = f2bf(tile[c4 + 3][r]);
    *(u16x4*)&out[(size_t)(n0 + r) * K + k0 + c4] = o;
}

// ---------------- GEMM: C[M][N] = A[M][K] * Bt[N][K]^T  (m97 structure) ----------------
// EPI 0: scatter epilogue into q_raw / k_raw / v_t(bf16, v transposed)
// EPI 1: f32 epilogue into outf[M][4096]
template<int EPI>
__global__ __launch_bounds__(256) void gemm_bt(
    const u16* __restrict__ A, const u16* __restrict__ Bt,
    u16* __restrict__ q_raw, u16* __restrict__ k_raw, u16* __restrict__ v_t,
    float* __restrict__ outf, int Kdim)
{
    __shared__ u16 ldsA[128 * 32];
    __shared__ u16 ldsB[128 * 32];
    int t = threadIdx.x, lane = t & 63, w = t >> 6;
    int wr = w >> 1, wc = w & 1;                 // 2x2 wave grid, 64x64 per wave
    int m0 = blockIdx.y * 128, n0 = blockIdx.x * 128;
    f32x4 acc[4][4] = {};

    for (int kt = 0; kt < Kdim; kt += 32) {
        // stage A,B tiles (each 128x32 bf16 = 8KB): 512 chunks of 16B each
        for (int i = 0; i < 2; ++i) {
            int cb = (i * 4 + w) * 64;           // wave-uniform chunk base
            int c  = cb + lane;
            gload_lds16(&A [(size_t)(m0 + (c >> 2)) * Kdim + kt + (c & 3) * 8], &ldsA[cb * 8]);
            gload_lds16(&Bt[(size_t)(n0 + (c >> 2)) * Kdim + kt + (c & 3) * 8], &ldsB[cb * 8]);
        }
        __syncthreads();
        short8 af[4], bfm[4];
        #pragma unroll
        for (int i = 0; i < 4; ++i)
            af[i] = *(const short8*)&ldsA[(wr * 64 + i * 16 + (lane & 15)) * 32 + (lane >> 4) * 8];
        #pragma unroll
        for (int j = 0; j < 4; ++j)
            bfm[j] = *(const short8*)&ldsB[(wc * 64 + j * 16 + (lane & 15)) * 32 + (lane >> 4) * 8];
        #pragma unroll
        for (int i = 0; i < 4; ++i)
            #pragma unroll
            for (int j = 0; j < 4; ++j)
                acc[i][j] = __builtin_amdgcn_mfma_f32_16x16x32_bf16(af[i], bfm[j], acc[i][j], 0, 0, 0);
        __syncthreads();
    }

    // epilogue: C/D layout col=lane&15, row=(lane>>4)*4+r  [m89-verified]
    #pragma unroll
    for (int i = 0; i < 4; ++i) {
        int mbase = m0 + wr * 64 + i * 16 + (lane >> 4) * 4;
        #pragma unroll
        for (int j = 0; j < 4; ++j) {
            int n = n0 + wc * 64 + j * 16 + (lane & 15);
            #pragma unroll
            for (int r = 0; r < 4; ++r) {
                int m = mbase + r;
                float val = acc[i][j][r];
                if (EPI == 0) {
                    int bb = m >> 11, s = m & (S_LEN - 1);
                    u16 bv = f2bf(val);
                    if (n < DIMC) {                      // q -> [B][NH][S][HD]
                        int h = n >> 7, d = n & 127;
                        q_raw[(((size_t)bb * NH + h) * S_LEN + s) * HD + d] = bv;
                    } else if (n < DIMC + NKV * HD) {    // k -> [B][NKV][S][HD]
                        int h = (n - DIMC) >> 7, d = n & 127;
                        k_raw[(((size_t)bb * NKV + h) * S_LEN + s) * HD + d] = bv;
                    } else {                             // v -> transposed [B][NKV][HD][S]
                        int h = (n - DIMC - NKV * HD) >> 7, d = n & 127;
                        v_t[(((size_t)bb * NKV + h) * HD + d) * S_LEN + s] = bv;
                    }
                } else {
                    outf[(size_t)m * DIMC + n] = val;
                }
            }
        }
    }
}

// ---------------- RoPE (in-place, bf16x8 chunks; 1/sqrt(HD) folded into q) ----------------
__global__ void rope_kernel(u16* __restrict__ q, u16* __restrict__ k,
                            const float* __restrict__ cosr, const float* __restrict__ sinr) {
    const int NQ = BATCH * NH * S_LEN * 16;      // 16 chunks of 8 elems per 128-d row
    const int NK = BATCH * NKV * S_LEN * 16;
    int idx = blockIdx.x * 256 + threadIdx.x;
    u16* ptr; int s; float scale; int ci;
    if (idx < NQ) {
        int row = idx >> 4; s = row & (S_LEN - 1);
        ptr = q + (size_t)idx * 8; scale = 0.08838834764831845f; ci = idx & 15;
    } else if (idx < NQ + NK) {
        int i2 = idx - NQ; int row = i2 >> 4; s = row & (S_LEN - 1);
        ptr = k + (size_t)i2 * 8; scale = 1.0f; ci = i2 & 15;
    } else return;
    int p0 = ci * 4;                              // pair index, multiple of 4
    fvec4 c  = *(const fvec4*)&cosr[s * 64 + p0];
    fvec4 sn = *(const fvec4*)&sinr[s * 64 + p0];
    short8 v = *(const short8*)ptr;
    short8 o;
    #pragma unroll
    for (int p = 0; p < 4; ++p) {
        float re = bf2f((u16)v[2 * p]), im = bf2f((u16)v[2 * p + 1]);
        o[2 * p]     = (short)f2bf((re * c[p] - im * sn[p]) * scale);
        o[2 * p + 1] = (short)f2bf((re * sn[p] + im * c[p]) * scale);
    }
    *(short8*)ptr = o;
}

// ---------------- flash attention ----------------
// grid (S/64, NH, B); 256 thr = 4 waves; wave owns 16 q-rows; full (non-causal) softmax.
__global__ __launch_bounds__(256) void attn_kernel(
    const u16* __restrict__ q_r, const u16* __restrict__ k_r,
    const u16* __restrict__ v_t, u16* __restrict__ att)
{
    __shared__ u16 p_lds[4][16 * 128];            // per-wave 16x128 bf16, XOR-swizzled
    int qt = blockIdx.x, h = blockIdx.y, b = blockIdx.z;
    int hkv = h >> 2;                              // N_REP = 4
    int t = threadIdx.x, lane = t & 63, w = t >> 6;
    const u16* Q = q_r + (((size_t)b * NH + h) * S_LEN + qt * 64 + w * 16) * HD;
    const u16* K = k_r + ((size_t)b * NKV + hkv) * S_LEN * HD;
    const u16* V = v_t + ((size_t)b * NKV + hkv) * HD * S_LEN;
    u16* pl = p_lds[w];

    // Q A-frags: row=lane&15, k=(lane>>4)*8 (+32 per ks)
    short8 qf[4];
    #pragma unroll
    for (int ks = 0; ks < 4; ++ks)
        qf[ks] = *(const short8*)&Q[(lane & 15) * HD + ks * 32 + (lane >> 4) * 8];

    float m_run[4] = {-1e30f, -1e30f, -1e30f, -1e30f};
    float l_run[4] = {0.f, 0.f, 0.f, 0.f};
    f32x4 acc_o[8] = {};

    for (int kv = 0; kv < S_LEN; kv += 128) {
        // S = Q K^T : 8 col-tiles of 16
        f32x4 accs[8] = {};
        #pragma unroll
        for (int ct = 0; ct < 8; ++ct) {
            const u16* Kc = &K[(size_t)(kv + ct * 16 + (lane & 15)) * HD + (lane >> 4) * 8];
            #pragma unroll
            for (int ks = 0; ks < 4; ++ks) {
                short8 kf = *(const short8*)&Kc[ks * 32];
                accs[ct] = __builtin_amdgcn_mfma_f32_16x16x32_bf16(qf[ks], kf, accs[ct], 0, 0, 0);
            }
        }
        // online softmax (rows live in (lane>>4)*4+j; 16 lanes of a group hold the 16 cols)
        float alpha[4];
        #pragma unroll
        for (int j = 0; j < 4; ++j) {
            float mx = accs[0][j];
            #pragma unroll
            for (int ct = 1; ct < 8; ++ct) mx = fmaxf(mx, accs[ct][j]);
            mx = fmaxf(mx, __shfl_xor(mx, 1, 64));
            mx = fmaxf(mx, __shfl_xor(mx, 2, 64));
            mx = fmaxf(mx, __shfl_xor(mx, 4, 64));
            mx = fmaxf(mx, __shfl_xor(mx, 8, 64));
            float mn = fmaxf(m_run[j], mx);
            alpha[j] = __expf(m_run[j] - mn);
            m_run[j] = mn;
        }
        float psum[4] = {0.f, 0.f, 0.f, 0.f};
        #pragma unroll
        for (int ct = 0; ct < 8; ++ct) {
            #pragma unroll
            for (int j = 0; j < 4; ++j) {
                float p = __expf(accs[ct][j] - m_run[j]);
                psum[j] += p;
                int row = (lane >> 4) * 4 + j;
                int col = ct * 16 + (lane & 15);
                int boff = row * 256 + ((col * 2) ^ ((row & 7) << 4));   // XOR swizzle
                *(u16*)((char*)pl + boff) = f2bf(p);
            }
        }
        #pragma unroll
        for (int j = 0; j < 4; ++j) {
            psum[j] += __shfl_xor(psum[j], 1, 64);
            psum[j] += __shfl_xor(psum[j], 2, 64);
            psum[j] += __shfl_xor(psum[j], 4, 64);
            psum[j] += __shfl_xor(psum[j], 8, 64);
            l_run[j] = l_run[j] * alpha[j] + psum[j];
        }
        #pragma unroll
        for (int dt = 0; dt < 8; ++dt)
            #pragma unroll
            for (int j = 0; j < 4; ++j) acc_o[dt][j] *= alpha[j];
        // PV: A = P (from swizzled LDS, same-wave ordering), B = V^T rows
        #pragma unroll
        for (int ks2 = 0; ks2 < 4; ++ks2) {
            int row = lane & 15;
            int cb = ks2 * 64 + (lane >> 4) * 16;                        // byte offset in row
            int boff = row * 256 + (cb ^ ((row & 7) << 4));
            short8 pf = *(const short8*)((const char*)pl + boff);
            #pragma unroll
            for (int dt = 0; dt < 8; ++dt) {
                short8 vf = *(const short8*)&V[(size_t)(dt * 16 + (lane & 15)) * S_LEN
                                               + kv + ks2 * 32 + (lane >> 4) * 8];
                acc_o[dt] = __builtin_amdgcn_mfma_f32_16x16x32_bf16(pf, vf, acc_o[dt], 0, 0, 0);
            }
        }
    }
    // epilogue -> att[B*S][4096] bf16
    #pragma unroll
    for (int j = 0; j < 4; ++j) {
        float rl = 1.f / l_run[j];
        int row = (lane >> 4) * 4 + j;
        size_t mrow = (size_t)b * S_LEN + qt * 64 + w * 16 + row;
        #pragma unroll
        for (int dt = 0; dt < 8; ++dt)
            att[mrow * DIMC + h * HD + dt * 16 + (lane & 15)] = f2bf(acc_o[dt][j] * rl);
    }
}

// ---------------- launch ----------------
extern "C" void kernel_launch(void* const* d_in, const int* in_sizes, int n_in,
                              void* d_out, int out_size, void* d_ws, size_t ws_size,
                              hipStream_t stream) {
    const float* x    = (const float*)d_in[0];
    const float* wq   = (const float*)d_in[1];
    const float* wk   = (const float*)d_in[2];
    const float* wv   = (const float*)d_in[3];
    const float* wo   = (const float*)d_in[4];
    const float* cosr = (const float*)d_in[7];
    const float* sinr = (const float*)d_in[8];
    // d_in[5]/d_in[6] (zero caches) and d_in[9] (start_pos==0) are not needed.
    float* out = (float*)d_out;

    char* ws = (char*)d_ws;
    u16* x_bf   = (u16*)(ws);                       //  32 MB: [4096][4096]
    u16* wqkv_t = (u16*)(ws + 33554432);            //  48 MB: [6144][4096]
    u16* wo_t   = (u16*)(ws + 83886080);            //  32 MB: [4096][4096]
    u16* q_r    = (u16*)(ws + 117440512);           //  32 MB: [B][NH][S][HD]
    u16* k_r    = (u16*)(ws + 150994944);           //   8 MB: [B][NKV][S][HD]
    u16* v_t    = (u16*)(ws + 159383552);           //   8 MB: [B][NKV][HD][S]
    u16* att    = (u16*)(ws + 167772160);           //  32 MB: [4096][4096]
    // total 192 MB of d_ws

    cvt_f32_bf16<<<16384, 256, 0, stream>>>(x, x_bf, (M_TOT * DIMC) / 4);
    transpose_cvt<<<dim3(128, 128), 256, 0, stream>>>(wq, wqkv_t, DIMC, 4096);
    transpose_cvt<<<dim3(32, 128), 256, 0, stream>>>(wk, wqkv_t + (size_t)4096 * DIMC, DIMC, 1024);
    transpose_cvt<<<dim3(32, 128), 256, 0, stream>>>(wv, wqkv_t + (size_t)5120 * DIMC, DIMC, 1024);
    transpose_cvt<<<dim3(128, 128), 256, 0, stream>>>(wo, wo_t, 4096, DIMC);

    gemm_bt<0><<<dim3(N_QKV / 128, M_TOT / 128), 256, 0, stream>>>(
        x_bf, wqkv_t, q_r, k_r, v_t, nullptr, DIMC);

    rope_kernel<<<(BATCH * (NH + NKV) * S_LEN * 16) / 256, 256, 0, stream>>>(q_r, k_r, cosr, sinr);

    attn_kernel<<<dim3(S_LEN / 64, NH, BATCH), 256, 0, stream>>>(q_r, k_r, v_t, att);

    gemm_bt<1><<<dim3(DIMC / 128, M_TOT / 128), 256, 0, stream>>>(
        att, wo_t, nullptr, nullptr, nullptr, out, DIMC);
}

// Round 2
// 1011.756 us; speedup vs baseline: 1.6401x; 1.6401x over previous
//
#include <hip/hip_runtime.h>

// ---------------- problem constants ----------------
#define S_LEN 2048
#define DIMC  4096
#define NH    32
#define NKV   8
#define HD    128
#define BATCH 2
#define M_TOT (BATCH*S_LEN)          // 4096 rows of x
#define N_QKV (DIMC + 2*NKV*HD)      // 6144 = 4096 q + 1024 k + 1024 v

typedef unsigned short u16;
typedef __attribute__((ext_vector_type(8))) short  short8;  // 8 bf16 (4 VGPRs)
typedef __attribute__((ext_vector_type(4))) float  f32x4;
typedef __attribute__((ext_vector_type(4))) float  fvec4;
typedef __attribute__((ext_vector_type(4))) unsigned short u16x4;

__device__ __forceinline__ u16 f2bf(float f) {
    union { float f; unsigned u; } v; v.f = f;
    unsigned r = v.u + 0x7FFFu + ((v.u >> 16) & 1u);   // RNE
    return (u16)(r >> 16);
}
__device__ __forceinline__ float bf2f(u16 h) {
    union { unsigned u; float f; } v; v.u = ((unsigned)h) << 16;
    return v.f;
}

// async global->LDS, 16B per lane; LDS dest = wave-uniform base + lane*16
__device__ __forceinline__ void gload_lds16(const void* g, void* l) {
    __builtin_amdgcn_global_load_lds(
        (const __attribute__((address_space(1))) void*)g,
        (__attribute__((address_space(3))) void*)l, 16, 0, 0);
}

// ---------------- stage 0: convert / transpose ----------------
__global__ void cvt_f32_bf16(const float* __restrict__ in, u16* __restrict__ out, int n4) {
    int i = blockIdx.x * 256 + threadIdx.x;
    if (i >= n4) return;
    fvec4 v = ((const fvec4*)in)[i];
    u16x4 o;
    o[0] = f2bf(v[0]); o[1] = f2bf(v[1]); o[2] = f2bf(v[2]); o[3] = f2bf(v[3]);
    ((u16x4*)out)[i] = o;
}

// out[n][k] = (bf16) in[k][n];  in is K x N f32
__global__ void transpose_cvt(const float* __restrict__ in, u16* __restrict__ out,
                              int K, int N) {
    __shared__ float tile[32][33];
    int k0 = blockIdx.y * 32, n0 = blockIdx.x * 32;
    int t = threadIdx.x;
    int r = t >> 3, c4 = (t & 7) * 4;
    fvec4 v = *(const fvec4*)&in[(size_t)(k0 + r) * N + n0 + c4];
    tile[r][c4 + 0] = v[0]; tile[r][c4 + 1] = v[1];
    tile[r][c4 + 2] = v[2]; tile[r][c4 + 3] = v[3];
    __syncthreads();
    u16x4 o;
    o[0] = f2bf(tile[c4 + 0][r]); o[1] = f2bf(tile[c4 + 1][r]);
    o[2] = f2bf(tile[c4 + 2][r]); o[3] = f2bf(tile[c4 + 3][r]);
    *(u16x4*)&out[(size_t)(n0 + r) * K + k0 + c4] = o;
}

// ---------------- GEMM: C[M][N] = A[M][K] * Bt[N][K]^T  (m97 structure) ----------------
template<int EPI>
__global__ __launch_bounds__(256) void gemm_bt(
    const u16* __restrict__ A, const u16* __restrict__ Bt,
    u16* __restrict__ q_raw, u16* __restrict__ k_raw, u16* __restrict__ v_t,
    float* __restrict__ outf, int Kdim)
{
    __shared__ u16 ldsA[128 * 32];
    __shared__ u16 ldsB[128 * 32];
    int t = threadIdx.x, lane = t & 63, w = t >> 6;
    int wr = w >> 1, wc = w & 1;                 // 2x2 wave grid, 64x64 per wave
    int m0 = blockIdx.y * 128, n0 = blockIdx.x * 128;
    f32x4 acc[4][4] = {};

    for (int kt = 0; kt < Kdim; kt += 32) {
        for (int i = 0; i < 2; ++i) {
            int cb = (i * 4 + w) * 64;           // wave-uniform chunk base
            int c  = cb + lane;
            gload_lds16(&A [(size_t)(m0 + (c >> 2)) * Kdim + kt + (c & 3) * 8], &ldsA[cb * 8]);
            gload_lds16(&Bt[(size_t)(n0 + (c >> 2)) * Kdim + kt + (c & 3) * 8], &ldsB[cb * 8]);
        }
        __syncthreads();
        short8 af[4], bfm[4];
        #pragma unroll
        for (int i = 0; i < 4; ++i)
            af[i] = *(const short8*)&ldsA[(wr * 64 + i * 16 + (lane & 15)) * 32 + (lane >> 4) * 8];
        #pragma unroll
        for (int j = 0; j < 4; ++j)
            bfm[j] = *(const short8*)&ldsB[(wc * 64 + j * 16 + (lane & 15)) * 32 + (lane >> 4) * 8];
        #pragma unroll
        for (int i = 0; i < 4; ++i)
            #pragma unroll
            for (int j = 0; j < 4; ++j)
                acc[i][j] = __builtin_amdgcn_mfma_f32_16x16x32_bf16(af[i], bfm[j], acc[i][j], 0, 0, 0);
        __syncthreads();
    }

    // epilogue: C/D layout col=lane&15, row=(lane>>4)*4+r
    #pragma unroll
    for (int i = 0; i < 4; ++i) {
        int mbase = m0 + wr * 64 + i * 16 + (lane >> 4) * 4;
        #pragma unroll
        for (int j = 0; j < 4; ++j) {
            int n = n0 + wc * 64 + j * 16 + (lane & 15);
            #pragma unroll
            for (int r = 0; r < 4; ++r) {
                int m = mbase + r;
                float val = acc[i][j][r];
                if (EPI == 0) {
                    int bb = m >> 11, s = m & (S_LEN - 1);
                    u16 bv = f2bf(val);
                    if (n < DIMC) {                      // q -> [B][NH][S][HD]
                        int h = n >> 7, d = n & 127;
                        q_raw[(((size_t)bb * NH + h) * S_LEN + s) * HD + d] = bv;
                    } else if (n < DIMC + NKV * HD) {    // k -> [B][NKV][S][HD]
                        int h = (n - DIMC) >> 7, d = n & 127;
                        k_raw[(((size_t)bb * NKV + h) * S_LEN + s) * HD + d] = bv;
                    } else {                             // v -> transposed [B][NKV][HD][S]
                        int h = (n - DIMC - NKV * HD) >> 7, d = n & 127;
                        v_t[(((size_t)bb * NKV + h) * HD + d) * S_LEN + s] = bv;
                    }
                } else {
                    outf[(size_t)m * DIMC + n] = val;
                }
            }
        }
    }
}

// ---------------- RoPE (in-place; 1/sqrt(HD) folded into q) ----------------
__global__ void rope_kernel(u16* __restrict__ q, u16* __restrict__ k,
                            const float* __restrict__ cosr, const float* __restrict__ sinr) {
    const int NQ = BATCH * NH * S_LEN * 16;
    const int NK = BATCH * NKV * S_LEN * 16;
    int idx = blockIdx.x * 256 + threadIdx.x;
    u16* ptr; int s; float scale; int ci;
    if (idx < NQ) {
        int row = idx >> 4; s = row & (S_LEN - 1);
        ptr = q + (size_t)idx * 8; scale = 0.08838834764831845f; ci = idx & 15;
    } else if (idx < NQ + NK) {
        int i2 = idx - NQ; int row = i2 >> 4; s = row & (S_LEN - 1);
        ptr = k + (size_t)i2 * 8; scale = 1.0f; ci = i2 & 15;
    } else return;
    int p0 = ci * 4;
    fvec4 c  = *(const fvec4*)&cosr[s * 64 + p0];
    fvec4 sn = *(const fvec4*)&sinr[s * 64 + p0];
    short8 v = *(const short8*)ptr;
    short8 o;
    #pragma unroll
    for (int p = 0; p < 4; ++p) {
        float re = bf2f((u16)v[2 * p]), im = bf2f((u16)v[2 * p + 1]);
        o[2 * p]     = (short)f2bf((re * c[p] - im * sn[p]) * scale);
        o[2 * p + 1] = (short)f2bf((re * sn[p] + im * c[p]) * scale);
    }
    *(short8*)ptr = o;
}

// ---------------- flash attention (LDS-staged, double-buffered) ----------------
// grid (S/128, NH, B); 256 thr = 4 waves; wave owns 32 q-rows; KV tile = 64.
// K tile [64][128] bf16, V^T tile [128][64] bf16, both XOR-swizzled
// (linear LDS dest for global_load_lds + pre-swizzled GLOBAL source, rule #21).
#define KVB 64
__global__ __launch_bounds__(256, 2) void attn_kernel(
    const u16* __restrict__ q_r, const u16* __restrict__ k_r,
    const u16* __restrict__ v_t, u16* __restrict__ att)
{
    __shared__ u16 kT[2][KVB * HD];        // 2 x 16 KB
    __shared__ u16 vT[2][HD * KVB];        // 2 x 16 KB
    __shared__ u16 pT[4][32 * KVB];        // 16 KB (per-wave P, swizzled)
    int qt = blockIdx.x, h = blockIdx.y, b = blockIdx.z;
    int hkv = h >> 2;                       // N_REP = 4
    int t = threadIdx.x, lane = t & 63, w = t >> 6;
    int g = lane >> 4, c16 = lane & 15;

    const u16* Q = q_r + (((size_t)b * NH + h) * S_LEN + qt * 128 + w * 32) * HD;
    const u16* K = k_r + ((size_t)b * NKV + hkv) * S_LEN * HD;
    const u16* V = v_t + ((size_t)b * NKV + hkv) * HD * S_LEN;
    u16* pl = pT[w];

    // Q A-frags in registers: rt 2 x ks 4; row = rt*16 + c16, k = ks*32 + g*8
    short8 qf[2][4];
    #pragma unroll
    for (int rt = 0; rt < 2; ++rt)
        #pragma unroll
        for (int ks = 0; ks < 4; ++ks)
            qf[rt][ks] = *(const short8*)&Q[(rt * 16 + c16) * HD + ks * 32 + g * 8];

    float m_run[2][4], l_run[2][4];
    #pragma unroll
    for (int rt = 0; rt < 2; ++rt)
        #pragma unroll
        for (int j = 0; j < 4; ++j) { m_run[rt][j] = -1e30f; l_run[rt][j] = 0.f; }
    f32x4 acc_o[2][8] = {};

    // stage tile 0
    #pragma unroll
    for (int i = 0; i < 4; ++i) {
        int cb = i * 256 + w * 64, c = cb + lane;
        { int row = c >> 4, lb = (c & 15) * 16, gb = lb ^ ((row & 7) << 4);
          gload_lds16(&K[(size_t)row * HD + (gb >> 1)], &kT[0][cb * 8]); }
        { int row = c >> 3, lb = (c & 7) * 16, gb = lb ^ ((row & 7) << 4);
          gload_lds16(&V[(size_t)row * S_LEN + (gb >> 1)], &vT[0][cb * 8]); }
    }
    __syncthreads();

    int buf = 0;
    for (int tt = 0; tt < S_LEN / KVB; ++tt) {
        // prefetch next tile into buf^1 (overlaps with compute below)
        if (tt < S_LEN / KVB - 1) {
            int kv0 = (tt + 1) * KVB;
            #pragma unroll
            for (int i = 0; i < 4; ++i) {
                int cb = i * 256 + w * 64, c = cb + lane;
                { int row = c >> 4, lb = (c & 15) * 16, gb = lb ^ ((row & 7) << 4);
                  gload_lds16(&K[(size_t)(kv0 + row) * HD + (gb >> 1)], &kT[buf ^ 1][cb * 8]); }
                { int row = c >> 3, lb = (c & 7) * 16, gb = lb ^ ((row & 7) << 4);
                  gload_lds16(&V[(size_t)row * S_LEN + kv0 + (gb >> 1)], &vT[buf ^ 1][cb * 8]); }
            }
        }
        const u16* kb = kT[buf];
        const u16* vb = vT[buf];

        // ---- QK^T: acc[rt][ct], rt = q row-tile, ct = kv col-tile ----
        f32x4 accs[2][4] = {};
        #pragma unroll
        for (int ks = 0; ks < 4; ++ks) {
            int lb = ks * 64 + g * 16;
            #pragma unroll
            for (int ct = 0; ct < 4; ++ct) {
                int r = ct * 16 + c16;
                short8 kf = *(const short8*)((const char*)kb + r * 256 + (lb ^ ((r & 7) << 4)));
                accs[0][ct] = __builtin_amdgcn_mfma_f32_16x16x32_bf16(qf[0][ks], kf, accs[0][ct], 0, 0, 0);
                accs[1][ct] = __builtin_amdgcn_mfma_f32_16x16x32_bf16(qf[1][ks], kf, accs[1][ct], 0, 0, 0);
            }
        }

        // ---- online softmax: row = rt*16 + g*4 + j, col = ct*16 + c16 ----
        float alpha[2][4];
        #pragma unroll
        for (int rt = 0; rt < 2; ++rt)
            #pragma unroll
            for (int j = 0; j < 4; ++j) {
                float mx = fmaxf(fmaxf(accs[rt][0][j], accs[rt][1][j]),
                                 fmaxf(accs[rt][2][j], accs[rt][3][j]));
                mx = fmaxf(mx, __shfl_xor(mx, 1, 64));
                mx = fmaxf(mx, __shfl_xor(mx, 2, 64));
                mx = fmaxf(mx, __shfl_xor(mx, 4, 64));
                mx = fmaxf(mx, __shfl_xor(mx, 8, 64));
                float mn = fmaxf(m_run[rt][j], mx);
                alpha[rt][j] = __expf(m_run[rt][j] - mn);
                m_run[rt][j] = mn;
            }
        // P = exp(S - m); store swizzled; accumulate LANE-LOCAL partial sums
        #pragma unroll
        for (int rt = 0; rt < 2; ++rt)
            #pragma unroll
            for (int j = 0; j < 4; ++j) {
                int row = rt * 16 + g * 4 + j;
                float ps = 0.f;
                #pragma unroll
                for (int ct = 0; ct < 4; ++ct) {
                    float p = __expf(accs[rt][ct][j] - m_run[rt][j]);
                    ps += p;
                    int boff = row * 128 + (((ct * 16 + c16) * 2) ^ ((row & 7) << 4));
                    *(u16*)((char*)pl + boff) = f2bf(p);
                }
                l_run[rt][j] = l_run[rt][j] * alpha[rt][j] + ps;   // lane-local partial
            }
        // rescale O
        #pragma unroll
        for (int rt = 0; rt < 2; ++rt)
            #pragma unroll
            for (int dt = 0; dt < 8; ++dt)
                #pragma unroll
                for (int j = 0; j < 4; ++j) acc_o[rt][dt][j] *= alpha[rt][j];

        // ---- PV: A = P[rt] (swizzled LDS), B = V^T rows ----
        #pragma unroll
        for (int ks2 = 0; ks2 < 2; ++ks2) {
            int lb = ks2 * 64 + g * 16;
            short8 pf[2];
            #pragma unroll
            for (int rt = 0; rt < 2; ++rt) {
                int row = rt * 16 + c16;
                pf[rt] = *(const short8*)((const char*)pl + row * 128 + (lb ^ ((row & 7) << 4)));
            }
            #pragma unroll
            for (int dt = 0; dt < 8; ++dt) {
                int r = dt * 16 + c16;
                short8 vf = *(const short8*)((const char*)vb + r * 128 + (lb ^ ((r & 7) << 4)));
                acc_o[0][dt] = __builtin_amdgcn_mfma_f32_16x16x32_bf16(pf[0], vf, acc_o[0][dt], 0, 0, 0);
                acc_o[1][dt] = __builtin_amdgcn_mfma_f32_16x16x32_bf16(pf[1], vf, acc_o[1][dt], 0, 0, 0);
            }
        }
        __syncthreads();
        buf ^= 1;
    }

    // ---- epilogue: reduce l across the 16-lane group, then write ----
    #pragma unroll
    for (int rt = 0; rt < 2; ++rt)
        #pragma unroll
        for (int j = 0; j < 4; ++j) {
            float l = l_run[rt][j];
            l += __shfl_xor(l, 1, 64);
            l += __shfl_xor(l, 2, 64);
            l += __shfl_xor(l, 4, 64);
            l += __shfl_xor(l, 8, 64);
            float rl = 1.f / l;
            size_t mrow = (size_t)b * S_LEN + qt * 128 + w * 32 + rt * 16 + g * 4 + j;
            #pragma unroll
            for (int dt = 0; dt < 8; ++dt)
                att[mrow * DIMC + h * HD + dt * 16 + c16] = f2bf(acc_o[rt][dt][j] * rl);
        }
}

// ---------------- launch ----------------
extern "C" void kernel_launch(void* const* d_in, const int* in_sizes, int n_in,
                              void* d_out, int out_size, void* d_ws, size_t ws_size,
                              hipStream_t stream) {
    const float* x    = (const float*)d_in[0];
    const float* wq   = (const float*)d_in[1];
    const float* wk   = (const float*)d_in[2];
    const float* wv   = (const float*)d_in[3];
    const float* wo   = (const float*)d_in[4];
    const float* cosr = (const float*)d_in[7];
    const float* sinr = (const float*)d_in[8];
    float* out = (float*)d_out;

    char* ws = (char*)d_ws;
    u16* x_bf   = (u16*)(ws);                       //  32 MB
    u16* wqkv_t = (u16*)(ws + 33554432);            //  48 MB
    u16* wo_t   = (u16*)(ws + 83886080);            //  32 MB
    u16* q_r    = (u16*)(ws + 117440512);           //  32 MB
    u16* k_r    = (u16*)(ws + 150994944);           //   8 MB
    u16* v_t    = (u16*)(ws + 159383552);           //   8 MB
    u16* att    = (u16*)(ws + 167772160);           //  32 MB

    cvt_f32_bf16<<<16384, 256, 0, stream>>>(x, x_bf, (M_TOT * DIMC) / 4);
    transpose_cvt<<<dim3(128, 128), 256, 0, stream>>>(wq, wqkv_t, DIMC, 4096);
    transpose_cvt<<<dim3(32, 128), 256, 0, stream>>>(wk, wqkv_t + (size_t)4096 * DIMC, DIMC, 1024);
    transpose_cvt<<<dim3(32, 128), 256, 0, stream>>>(wv, wqkv_t + (size_t)5120 * DIMC, DIMC, 1024);
    transpose_cvt<<<dim3(128, 128), 256, 0, stream>>>(wo, wo_t, 4096, DIMC);

    gemm_bt<0><<<dim3(N_QKV / 128, M_TOT / 128), 256, 0, stream>>>(
        x_bf, wqkv_t, q_r, k_r, v_t, nullptr, DIMC);

    rope_kernel<<<(BATCH * (NH + NKV) * S_LEN * 16) / 256, 256, 0, stream>>>(q_r, k_r, cosr, sinr);

    attn_kernel<<<dim3(S_LEN / 128, NH, BATCH), 256, 0, stream>>>(q_r, k_r, v_t, att);

    gemm_bt<1><<<dim3(DIMC / 128, M_TOT / 128), 256, 0, stream>>>(
        att, wo_t, nullptr, nullptr, nullptr, out, DIMC);
}

// Round 3
// 867.078 us; speedup vs baseline: 1.9137x; 1.1669x over previous
//
#include <hip/hip_runtime.h>

// ---------------- problem constants ----------------
#define S_LEN 2048
#define DIMC  4096
#define NH    32
#define NKV   8
#define HD    128
#define BATCH 2
#define M_TOT (BATCH*S_LEN)          // 4096 rows of x
#define N_QKV (DIMC + 2*NKV*HD)      // 6144

typedef unsigned short u16;
typedef unsigned int   uint32;
typedef __attribute__((ext_vector_type(8))) short  short8;
typedef __attribute__((ext_vector_type(4))) float  f32x4;
typedef __attribute__((ext_vector_type(4))) float  fvec4;
typedef __attribute__((ext_vector_type(4))) unsigned short u16x4;

__device__ __forceinline__ u16 f2bf(float f) {
    union { float f; unsigned u; } v; v.f = f;
    unsigned r = v.u + 0x7FFFu + ((v.u >> 16) & 1u);   // RNE
    return (u16)(r >> 16);
}
__device__ __forceinline__ float bf2f(u16 h) {
    union { unsigned u; float f; } v; v.u = ((unsigned)h) << 16;
    return v.f;
}

__device__ __forceinline__ void gload_lds16(const void* g, void* l) {
    __builtin_amdgcn_global_load_lds(
        (const __attribute__((address_space(1))) void*)g,
        (__attribute__((address_space(3))) void*)l, 16, 0, 0);
}

// ---------------- stage 0: convert / transpose ----------------
__global__ void cvt_f32_bf16(const float* __restrict__ in, u16* __restrict__ out, int n4) {
    int i = blockIdx.x * 256 + threadIdx.x;
    if (i >= n4) return;
    fvec4 v = ((const fvec4*)in)[i];
    u16x4 o;
    o[0] = f2bf(v[0]); o[1] = f2bf(v[1]); o[2] = f2bf(v[2]); o[3] = f2bf(v[3]);
    ((u16x4*)out)[i] = o;
}

__global__ void transpose_cvt(const float* __restrict__ in, u16* __restrict__ out,
                              int K, int N) {
    __shared__ float tile[32][33];
    int k0 = blockIdx.y * 32, n0 = blockIdx.x * 32;
    int t = threadIdx.x;
    int r = t >> 3, c4 = (t & 7) * 4;
    fvec4 v = *(const fvec4*)&in[(size_t)(k0 + r) * N + n0 + c4];
    tile[r][c4 + 0] = v[0]; tile[r][c4 + 1] = v[1];
    tile[r][c4 + 2] = v[2]; tile[r][c4 + 3] = v[3];
    __syncthreads();
    u16x4 o;
    o[0] = f2bf(tile[c4 + 0][r]); o[1] = f2bf(tile[c4 + 1][r]);
    o[2] = f2bf(tile[c4 + 2][r]); o[3] = f2bf(tile[c4 + 3][r]);
    *(u16x4*)&out[(size_t)(n0 + r) * K + k0 + c4] = o;
}

// ---------------- 256x256 8-phase GEMM (T2+T3+T4+T5) ----------------
// C[M][N] = A[M][K] * Bt[N][K]^T.  512 thr = 8 waves (2M x 4N), BK=64.
// LDS 128 KB: [buf 2][mat 2][half 2][subtile 16][1024B]; subtile = 16 rows x 32 elems,
// st_16x32 swizzle: byte col ^= 32 if (row&8), applied via pre-swizzled global src.
#define FEN asm volatile("" ::: "memory")
#define BAR1 do { FEN; __builtin_amdgcn_s_barrier(); \
                  asm volatile("s_waitcnt lgkmcnt(0)" ::: "memory"); } while(0)
#define BAR2 do { FEN; __builtin_amdgcn_s_barrier(); FEN; } while(0)

#define LDA(bufc, mh) do { _Pragma("unroll") for (int q_=0;q_<4;++q_) \
    _Pragma("unroll") for (int ks_=0;ks_<2;++ks_) \
    a[q_][ks_] = *(const short8*)(lds + ((bufc)*65536 + ((mh)*4+q_)*2048 + ks_*1024) + aB); } while(0)

#define LDB(bs, bufc, nh) do { _Pragma("unroll") for (int p_=0;p_<2;++p_) \
    _Pragma("unroll") for (int ks_=0;ks_<2;++ks_) \
    bs[p_][ks_] = *(const short8*)(lds + ((bufc)*65536 + ((nh)*2+p_)*2048 + ks_*1024) + bB); } while(0)

#define MM(mh, nh, bs) do { __builtin_amdgcn_s_setprio(1); \
  _Pragma("unroll") for (int ks_=0;ks_<2;++ks_) \
  _Pragma("unroll") for (int q_=0;q_<4;++q_) \
  _Pragma("unroll") for (int p_=0;p_<2;++p_) \
    acc[(mh)*4+q_][(nh)*2+p_] = __builtin_amdgcn_mfma_f32_16x16x32_bf16( \
        a[q_][ks_], bs[p_][ks_], acc[(mh)*4+q_][(nh)*2+p_], 0, 0, 0); \
  __builtin_amdgcn_s_setprio(0); } while(0)

// stage one half-tile (this wave's 2 subtiles) of mat (0=A,1=B) into bufS, tile t
#define STG(mat, half, bufS, t) do { \
    const char* gp_ = (mat) ? (const char*)Bt : (const char*)A; \
    const uint32* go_ = (mat) ? goB[half] : goA[half]; \
    gload_lds16(gp_ + (size_t)go_[0] + (size_t)(t)*128, \
                lds + ((bufS)*65536 + (mat)*32768 + (half)*16384) + s0*1024); \
    gload_lds16(gp_ + (size_t)go_[1] + (size_t)(t)*128, \
                lds + ((bufS)*65536 + (mat)*32768 + (half)*16384) + s1*1024); \
} while(0)

template<int EPI>
__global__ __launch_bounds__(512, 2) void gemm256(
    const u16* __restrict__ A, const u16* __restrict__ Bt,
    u16* __restrict__ q_raw, u16* __restrict__ k_raw, u16* __restrict__ v_t,
    float* __restrict__ outf, int Kdim)
{
    __shared__ __align__(16) char lds[131072];
    const int t = threadIdx.x, lane = t & 63, w = t >> 6;
    const int wm = w >> 2, wn = w & 3;
    const int c16 = lane & 15, g = lane >> 4;
    const int m0 = blockIdx.y * 256, n0 = blockIdx.x * 256;
    const int K2 = Kdim * 2;
    const int NT = Kdim >> 6, NITER = NT >> 1;

    // frag-read lane byte (swizzled): row=c16 within subtile, logical kbyte=g*16
    const int lanebyte = c16 * 64 + ((g * 16) ^ ((c16 & 8) << 2));
    const int aB = wm * 16384 + lanebyte;
    const int bB = 32768 + (wn >> 1) * 16384 + (wn & 1) * 8192 + lanebyte;

    // staging: wave w fills subtiles s0=w, s1=w+8; lane l -> row l>>2,
    // kbyte ((l&3)*16) ^ ((l>=32)*32)  (st_16x32 pre-swizzle on global src)
    const int s0 = w, s1 = w + 8;
    const int stg_swz = ((lane & 3) * 16) ^ ((lane >> 5) << 5);
    uint32 goA[2][2], goB[2][2];
    #pragma unroll
    for (int h = 0; h < 2; ++h)
        #pragma unroll
        for (int ii = 0; ii < 2; ++ii) {
            int s = w + ii * 8;
            int rr = h * 128 + (s >> 1) * 16 + (lane >> 2);
            int kb = (s & 1) * 64 + stg_swz;
            goA[h][ii] = (uint32)(m0 + rr) * K2 + kb;
            goB[h][ii] = (uint32)(n0 + rr) * K2 + kb;
        }

    f32x4 acc[8][4] = {};
    short8 a[4][2], b0[2][2], b1[2][2];

    // prologue: buf0 <- tile0 (all 4 half-tiles), buf1 <- tile1 (Bh0, Ah0)
    STG(1, 0, 0, 0); STG(0, 0, 0, 0); STG(1, 1, 0, 0); STG(0, 1, 0, 0);
    STG(1, 0, 1, 1); STG(0, 0, 1, 1);
    asm volatile("s_waitcnt vmcnt(4)" ::: "memory");
    BAR2;

    for (int it = 0; it < NITER; ++it) {
        const int T1 = 2 * it + 1;
        const int TN = 2 * it + 2;
        const bool nl = (it < NITER - 1);
        // phase 1: quad(0,0) of buf0
        LDA(0, 0); LDB(b0, 0, 0);
        STG(1, 1, 1, T1);                    // buf1.Bh1 <- T1
        BAR1; MM(0, 0, b0); BAR2;
        // phase 2: quad(0,1)
        LDB(b1, 0, 1);
        STG(0, 1, 1, T1);                    // buf1.Ah1 <- T1
        BAR1; MM(0, 1, b1); BAR2;
        // phase 3: quad(1,1)
        LDA(0, 1);
        if (nl) STG(1, 0, 0, TN);            // buf0.Bh0 <- TN
        BAR1; MM(1, 1, b1); BAR2;
        // phase 4: quad(1,0)
        if (nl) { STG(0, 0, 0, TN);          // buf0.Ah0 <- TN
                  asm volatile("s_waitcnt vmcnt(4)" ::: "memory"); }
        else    { asm volatile("s_waitcnt vmcnt(0)" ::: "memory"); }
        BAR1; MM(1, 0, b0); BAR2;
        // phase 5: quad(0,0) of buf1
        LDA(1, 0); LDB(b0, 1, 0);
        if (nl) STG(1, 1, 0, TN);            // buf0.Bh1 <- TN
        BAR1; MM(0, 0, b0); BAR2;
        // phase 6: quad(0,1)
        LDB(b1, 1, 1);
        if (nl) STG(0, 1, 0, TN);            // buf0.Ah1 <- TN
        BAR1; MM(0, 1, b1); BAR2;
        // phase 7: quad(1,1)
        LDA(1, 1);
        if (nl) STG(1, 0, 1, TN + 1);        // buf1.Bh0 <- TN+1
        BAR1; MM(1, 1, b1); BAR2;
        // phase 8: quad(1,0)
        if (nl) STG(0, 0, 1, TN + 1);        // buf1.Ah0 <- TN+1
        asm volatile("s_waitcnt vmcnt(4)" ::: "memory");
        BAR1; MM(1, 0, b0); BAR2;
    }

    // epilogue: C/D layout col=lane&15, row=(lane>>4)*4+r
    #pragma unroll
    for (int fm = 0; fm < 8; ++fm) {
        int mbase = m0 + wm * 128 + fm * 16 + g * 4;
        #pragma unroll
        for (int fn = 0; fn < 4; ++fn) {
            int n = n0 + wn * 64 + fn * 16 + c16;
            #pragma unroll
            for (int r = 0; r < 4; ++r) {
                int m = mbase + r;
                float val = acc[fm][fn][r];
                if (EPI == 0) {
                    int bb = m >> 11, s = m & (S_LEN - 1);
                    u16 bv = f2bf(val);
                    if (n < DIMC) {
                        int h = n >> 7, d = n & 127;
                        q_raw[(((size_t)bb * NH + h) * S_LEN + s) * HD + d] = bv;
                    } else if (n < DIMC + NKV * HD) {
                        int h = (n - DIMC) >> 7, d = n & 127;
                        k_raw[(((size_t)bb * NKV + h) * S_LEN + s) * HD + d] = bv;
                    } else {
                        int h = (n - DIMC - NKV * HD) >> 7, d = n & 127;
                        v_t[(((size_t)bb * NKV + h) * HD + d) * S_LEN + s] = bv;
                    }
                } else {
                    outf[(size_t)m * DIMC + n] = val;
                }
            }
        }
    }
}

// ---------------- RoPE (in-place; 1/sqrt(HD) folded into q) ----------------
__global__ void rope_kernel(u16* __restrict__ q, u16* __restrict__ k,
                            const float* __restrict__ cosr, const float* __restrict__ sinr) {
    const int NQ = BATCH * NH * S_LEN * 16;
    const int NK = BATCH * NKV * S_LEN * 16;
    int idx = blockIdx.x * 256 + threadIdx.x;
    u16* ptr; int s; float scale; int ci;
    if (idx < NQ) {
        int row = idx >> 4; s = row & (S_LEN - 1);
        ptr = q + (size_t)idx * 8; scale = 0.08838834764831845f; ci = idx & 15;
    } else if (idx < NQ + NK) {
        int i2 = idx - NQ; int row = i2 >> 4; s = row & (S_LEN - 1);
        ptr = k + (size_t)i2 * 8; scale = 1.0f; ci = i2 & 15;
    } else return;
    int p0 = ci * 4;
    fvec4 c  = *(const fvec4*)&cosr[s * 64 + p0];
    fvec4 sn = *(const fvec4*)&sinr[s * 64 + p0];
    short8 v = *(const short8*)ptr;
    short8 o;
    #pragma unroll
    for (int p = 0; p < 4; ++p) {
        float re = bf2f((u16)v[2 * p]), im = bf2f((u16)v[2 * p + 1]);
        o[2 * p]     = (short)f2bf((re * c[p] - im * sn[p]) * scale);
        o[2 * p + 1] = (short)f2bf((re * sn[p] + im * c[p]) * scale);
    }
    *(short8*)ptr = o;
}

// ---------------- flash attention (unchanged from round 2) ----------------
#define KVB 64
__global__ __launch_bounds__(256, 2) void attn_kernel(
    const u16* __restrict__ q_r, const u16* __restrict__ k_r,
    const u16* __restrict__ v_t, u16* __restrict__ att)
{
    __shared__ u16 kT[2][KVB * HD];
    __shared__ u16 vT[2][HD * KVB];
    __shared__ u16 pT[4][32 * KVB];
    int qt = blockIdx.x, h = blockIdx.y, b = blockIdx.z;
    int hkv = h >> 2;
    int t = threadIdx.x, lane = t & 63, w = t >> 6;
    int g = lane >> 4, c16 = lane & 15;

    const u16* Q = q_r + (((size_t)b * NH + h) * S_LEN + qt * 128 + w * 32) * HD;
    const u16* K = k_r + ((size_t)b * NKV + hkv) * S_LEN * HD;
    const u16* V = v_t + ((size_t)b * NKV + hkv) * HD * S_LEN;
    u16* pl = pT[w];

    short8 qf[2][4];
    #pragma unroll
    for (int rt = 0; rt < 2; ++rt)
        #pragma unroll
        for (int ks = 0; ks < 4; ++ks)
            qf[rt][ks] = *(const short8*)&Q[(rt * 16 + c16) * HD + ks * 32 + g * 8];

    float m_run[2][4], l_run[2][4];
    #pragma unroll
    for (int rt = 0; rt < 2; ++rt)
        #pragma unroll
        for (int j = 0; j < 4; ++j) { m_run[rt][j] = -1e30f; l_run[rt][j] = 0.f; }
    f32x4 acc_o[2][8] = {};

    #pragma unroll
    for (int i = 0; i < 4; ++i) {
        int cb = i * 256 + w * 64, c = cb + lane;
        { int row = c >> 4, lb = (c & 15) * 16, gb = lb ^ ((row & 7) << 4);
          gload_lds16(&K[(size_t)row * HD + (gb >> 1)], &kT[0][cb * 8]); }
        { int row = c >> 3, lb = (c & 7) * 16, gb = lb ^ ((row & 7) << 4);
          gload_lds16(&V[(size_t)row * S_LEN + (gb >> 1)], &vT[0][cb * 8]); }
    }
    __syncthreads();

    int buf = 0;
    for (int tt = 0; tt < S_LEN / KVB; ++tt) {
        if (tt < S_LEN / KVB - 1) {
            int kv0 = (tt + 1) * KVB;
            #pragma unroll
            for (int i = 0; i < 4; ++i) {
                int cb = i * 256 + w * 64, c = cb + lane;
                { int row = c >> 4, lb = (c & 15) * 16, gb = lb ^ ((row & 7) << 4);
                  gload_lds16(&K[(size_t)(kv0 + row) * HD + (gb >> 1)], &kT[buf ^ 1][cb * 8]); }
                { int row = c >> 3, lb = (c & 7) * 16, gb = lb ^ ((row & 7) << 4);
                  gload_lds16(&V[(size_t)row * S_LEN + kv0 + (gb >> 1)], &vT[buf ^ 1][cb * 8]); }
            }
        }
        const u16* kb = kT[buf];
        const u16* vb = vT[buf];

        f32x4 accs[2][4] = {};
        #pragma unroll
        for (int ks = 0; ks < 4; ++ks) {
            int lb = ks * 64 + g * 16;
            #pragma unroll
            for (int ct = 0; ct < 4; ++ct) {
                int r = ct * 16 + c16;
                short8 kf = *(const short8*)((const char*)kb + r * 256 + (lb ^ ((r & 7) << 4)));
                accs[0][ct] = __builtin_amdgcn_mfma_f32_16x16x32_bf16(qf[0][ks], kf, accs[0][ct], 0, 0, 0);
                accs[1][ct] = __builtin_amdgcn_mfma_f32_16x16x32_bf16(qf[1][ks], kf, accs[1][ct], 0, 0, 0);
            }
        }

        float alpha[2][4];
        #pragma unroll
        for (int rt = 0; rt < 2; ++rt)
            #pragma unroll
            for (int j = 0; j < 4; ++j) {
                float mx = fmaxf(fmaxf(accs[rt][0][j], accs[rt][1][j]),
                                 fmaxf(accs[rt][2][j], accs[rt][3][j]));
                mx = fmaxf(mx, __shfl_xor(mx, 1, 64));
                mx = fmaxf(mx, __shfl_xor(mx, 2, 64));
                mx = fmaxf(mx, __shfl_xor(mx, 4, 64));
                mx = fmaxf(mx, __shfl_xor(mx, 8, 64));
                float mn = fmaxf(m_run[rt][j], mx);
                alpha[rt][j] = __expf(m_run[rt][j] - mn);
                m_run[rt][j] = mn;
            }
        #pragma unroll
        for (int rt = 0; rt < 2; ++rt)
            #pragma unroll
            for (int j = 0; j < 4; ++j) {
                int row = rt * 16 + g * 4 + j;
                float ps = 0.f;
                #pragma unroll
                for (int ct = 0; ct < 4; ++ct) {
                    float p = __expf(accs[rt][ct][j] - m_run[rt][j]);
                    ps += p;
                    int boff = row * 128 + (((ct * 16 + c16) * 2) ^ ((row & 7) << 4));
                    *(u16*)((char*)pl + boff) = f2bf(p);
                }
                l_run[rt][j] = l_run[rt][j] * alpha[rt][j] + ps;
            }
        #pragma unroll
        for (int rt = 0; rt < 2; ++rt)
            #pragma unroll
            for (int dt = 0; dt < 8; ++dt)
                #pragma unroll
                for (int j = 0; j < 4; ++j) acc_o[rt][dt][j] *= alpha[rt][j];

        #pragma unroll
        for (int ks2 = 0; ks2 < 2; ++ks2) {
            int lb = ks2 * 64 + g * 16;
            short8 pf[2];
            #pragma unroll
            for (int rt = 0; rt < 2; ++rt) {
                int row = rt * 16 + c16;
                pf[rt] = *(const short8*)((const char*)pl + row * 128 + (lb ^ ((row & 7) << 4)));
            }
            #pragma unroll
            for (int dt = 0; dt < 8; ++dt) {
                int r = dt * 16 + c16;
                short8 vf = *(const short8*)((const char*)vb + r * 128 + (lb ^ ((r & 7) << 4)));
                acc_o[0][dt] = __builtin_amdgcn_mfma_f32_16x16x32_bf16(pf[0], vf, acc_o[0][dt], 0, 0, 0);
                acc_o[1][dt] = __builtin_amdgcn_mfma_f32_16x16x32_bf16(pf[1], vf, acc_o[1][dt], 0, 0, 0);
            }
        }
        __syncthreads();
        buf ^= 1;
    }

    #pragma unroll
    for (int rt = 0; rt < 2; ++rt)
        #pragma unroll
        for (int j = 0; j < 4; ++j) {
            float l = l_run[rt][j];
            l += __shfl_xor(l, 1, 64);
            l += __shfl_xor(l, 2, 64);
            l += __shfl_xor(l, 4, 64);
            l += __shfl_xor(l, 8, 64);
            float rl = 1.f / l;
            size_t mrow = (size_t)b * S_LEN + qt * 128 + w * 32 + rt * 16 + g * 4 + j;
            #pragma unroll
            for (int dt = 0; dt < 8; ++dt)
                att[mrow * DIMC + h * HD + dt * 16 + c16] = f2bf(acc_o[rt][dt][j] * rl);
        }
}

// ---------------- launch ----------------
extern "C" void kernel_launch(void* const* d_in, const int* in_sizes, int n_in,
                              void* d_out, int out_size, void* d_ws, size_t ws_size,
                              hipStream_t stream) {
    const float* x    = (const float*)d_in[0];
    const float* wq   = (const float*)d_in[1];
    const float* wk   = (const float*)d_in[2];
    const float* wv   = (const float*)d_in[3];
    const float* wo   = (const float*)d_in[4];
    const float* cosr = (const float*)d_in[7];
    const float* sinr = (const float*)d_in[8];
    float* out = (float*)d_out;

    char* ws = (char*)d_ws;
    u16* x_bf   = (u16*)(ws);                       //  32 MB
    u16* wqkv_t = (u16*)(ws + 33554432);            //  48 MB
    u16* wo_t   = (u16*)(ws + 83886080);            //  32 MB
    u16* q_r    = (u16*)(ws + 117440512);           //  32 MB
    u16* k_r    = (u16*)(ws + 150994944);           //   8 MB
    u16* v_t    = (u16*)(ws + 159383552);           //   8 MB
    u16* att    = (u16*)(ws + 167772160);           //  32 MB

    cvt_f32_bf16<<<16384, 256, 0, stream>>>(x, x_bf, (M_TOT * DIMC) / 4);
    transpose_cvt<<<dim3(128, 128), 256, 0, stream>>>(wq, wqkv_t, DIMC, 4096);
    transpose_cvt<<<dim3(32, 128), 256, 0, stream>>>(wk, wqkv_t + (size_t)4096 * DIMC, DIMC, 1024);
    transpose_cvt<<<dim3(32, 128), 256, 0, stream>>>(wv, wqkv_t + (size_t)5120 * DIMC, DIMC, 1024);
    transpose_cvt<<<dim3(128, 128), 256, 0, stream>>>(wo, wo_t, 4096, DIMC);

    gemm256<0><<<dim3(N_QKV / 256, M_TOT / 256), 512, 0, stream>>>(
        x_bf, wqkv_t, q_r, k_r, v_t, nullptr, DIMC);

    rope_kernel<<<(BATCH * (NH + NKV) * S_LEN * 16) / 256, 256, 0, stream>>>(q_r, k_r, cosr, sinr);

    attn_kernel<<<dim3(S_LEN / 128, NH, BATCH), 256, 0, stream>>>(q_r, k_r, v_t, att);

    gemm256<1><<<dim3(DIMC / 256, M_TOT / 256), 512, 0, stream>>>(
        att, wo_t, nullptr, nullptr, nullptr, out, DIMC);
}

// Round 5
// 781.811 us; speedup vs baseline: 2.1224x; 1.1091x over previous
//
#include <hip/hip_runtime.h>

// ---------------- problem constants ----------------
#define S_LEN 2048
#define DIMC  4096
#define NH    32
#define NKV   8
#define HD    128
#define BATCH 2
#define M_TOT (BATCH*S_LEN)          // 4096 rows of x
#define N_QKV (DIMC + 2*NKV*HD)      // 6144

typedef unsigned short u16;
typedef unsigned int   uint32;
typedef __attribute__((ext_vector_type(8)))  short short8;
typedef __attribute__((ext_vector_type(4)))  float f32x4;
typedef __attribute__((ext_vector_type(16))) float f32x16;
typedef __attribute__((ext_vector_type(4)))  float fvec4;
typedef __attribute__((ext_vector_type(4)))  unsigned short u16x4;

__device__ __forceinline__ u16 f2bf(float f) {
    union { float f; unsigned u; } v; v.f = f;
    unsigned r = v.u + 0x7FFFu + ((v.u >> 16) & 1u);   // RNE
    return (u16)(r >> 16);
}
__device__ __forceinline__ float bf2f(u16 h) {
    union { unsigned u; float f; } v; v.u = ((unsigned)h) << 16;
    return v.f;
}
// 2^x via v_exp_f32 (gfx950 v_exp_f32 IS base-2); avoids glibc __exp2f name clash
__device__ __forceinline__ float exp2_fast(float x) {
    return __builtin_amdgcn_exp2f(x);
}
__device__ __forceinline__ unsigned cvtpk_bf16(float lo, float hi) {
    unsigned r;
    asm volatile("v_cvt_pk_bf16_f32 %0, %1, %2" : "=v"(r) : "v"(lo), "v"(hi));
    return r;
}
__device__ __forceinline__ void pl32swap(unsigned &a, unsigned &b) {
    // swaps a[lanes 32:63] with b[lanes 0:31]
    asm volatile("v_permlane32_swap_b32 %0, %1" : "+v"(a), "+v"(b));
}

// async global->LDS, 16B per lane; LDS dest = wave-uniform base + lane*16
__device__ __forceinline__ void gload_lds16(const void* g, void* l) {
    __builtin_amdgcn_global_load_lds(
        (const __attribute__((address_space(1))) void*)g,
        (__attribute__((address_space(3))) void*)l, 16, 0, 0);
}

// ---------------- stage 0: convert / transpose ----------------
__global__ void cvt_f32_bf16(const float* __restrict__ in, u16* __restrict__ out, int n4) {
    int i = blockIdx.x * 256 + threadIdx.x;
    if (i >= n4) return;
    fvec4 v = ((const fvec4*)in)[i];
    u16x4 o;
    o[0] = f2bf(v[0]); o[1] = f2bf(v[1]); o[2] = f2bf(v[2]); o[3] = f2bf(v[3]);
    ((u16x4*)out)[i] = o;
}

__global__ void transpose_cvt(const float* __restrict__ in, u16* __restrict__ out,
                              int K, int N) {
    __shared__ float tile[32][33];
    int k0 = blockIdx.y * 32, n0 = blockIdx.x * 32;
    int t = threadIdx.x;
    int r = t >> 3, c4 = (t & 7) * 4;
    fvec4 v = *(const fvec4*)&in[(size_t)(k0 + r) * N + n0 + c4];
    tile[r][c4 + 0] = v[0]; tile[r][c4 + 1] = v[1];
    tile[r][c4 + 2] = v[2]; tile[r][c4 + 3] = v[3];
    __syncthreads();
    u16x4 o;
    o[0] = f2bf(tile[c4 + 0][r]); o[1] = f2bf(tile[c4 + 1][r]);
    o[2] = f2bf(tile[c4 + 2][r]); o[3] = f2bf(tile[c4 + 3][r]);
    *(u16x4*)&out[(size_t)(n0 + r) * K + k0 + c4] = o;
}

// ---------------- 256x256 8-phase GEMM (T1+T2+T3+T4+T5) ----------------
#define FEN asm volatile("" ::: "memory")
#define BAR1 do { FEN; __builtin_amdgcn_s_barrier(); \
                  asm volatile("s_waitcnt lgkmcnt(0)" ::: "memory"); } while(0)
#define BAR2 do { FEN; __builtin_amdgcn_s_barrier(); FEN; } while(0)

#define LDA(bufc, mh) do { _Pragma("unroll") for (int q_=0;q_<4;++q_) \
    _Pragma("unroll") for (int ks_=0;ks_<2;++ks_) \
    a[q_][ks_] = *(const short8*)(lds + ((bufc)*65536 + ((mh)*4+q_)*2048 + ks_*1024) + aB); } while(0)

#define LDB(bs, bufc, nh) do { _Pragma("unroll") for (int p_=0;p_<2;++p_) \
    _Pragma("unroll") for (int ks_=0;ks_<2;++ks_) \
    bs[p_][ks_] = *(const short8*)(lds + ((bufc)*65536 + ((nh)*2+p_)*2048 + ks_*1024) + bB); } while(0)

#define MM(mh, nh, bs) do { __builtin_amdgcn_s_setprio(1); \
  _Pragma("unroll") for (int ks_=0;ks_<2;++ks_) \
  _Pragma("unroll") for (int q_=0;q_<4;++q_) \
  _Pragma("unroll") for (int p_=0;p_<2;++p_) \
    acc[(mh)*4+q_][(nh)*2+p_] = __builtin_amdgcn_mfma_f32_16x16x32_bf16( \
        a[q_][ks_], bs[p_][ks_], acc[(mh)*4+q_][(nh)*2+p_], 0, 0, 0); \
  __builtin_amdgcn_s_setprio(0); } while(0)

#define STG(mat, half, bufS, t) do { \
    const char* gp_ = (mat) ? (const char*)Bt : (const char*)A; \
    const uint32* go_ = (mat) ? goB[half] : goA[half]; \
    gload_lds16(gp_ + (size_t)go_[0] + (size_t)(t)*128, \
                lds + ((bufS)*65536 + (mat)*32768 + (half)*16384) + s0*1024); \
    gload_lds16(gp_ + (size_t)go_[1] + (size_t)(t)*128, \
                lds + ((bufS)*65536 + (mat)*32768 + (half)*16384) + s1*1024); \
} while(0)

template<int EPI>
__global__ __launch_bounds__(512, 2) void gemm256(
    const u16* __restrict__ A, const u16* __restrict__ Bt,
    u16* __restrict__ q_raw, u16* __restrict__ k_raw, u16* __restrict__ v_t,
    float* __restrict__ outf, int Kdim)
{
    __shared__ __align__(16) char lds[131072];
    const int t = threadIdx.x, lane = t & 63, w = t >> 6;
    const int wm = w >> 2, wn = w & 3;
    const int c16 = lane & 15, g = lane >> 4;

    // T1: bijective XCD swizzle (nwg % 8 == 0 for both our grids)
    const int nwgx = gridDim.x, nwg = nwgx * gridDim.y;
    int orig = blockIdx.y * nwgx + blockIdx.x;
    int cpx = nwg >> 3;
    int wg = (orig & 7) * cpx + (orig >> 3);
    const int m0 = (wg / nwgx) * 256, n0 = (wg % nwgx) * 256;

    const int K2 = Kdim * 2;
    const int NITER = Kdim >> 7;

    const int lanebyte = c16 * 64 + ((g * 16) ^ ((c16 & 8) << 2));
    const int aB = wm * 16384 + lanebyte;
    const int bB = 32768 + (wn >> 1) * 16384 + (wn & 1) * 8192 + lanebyte;

    const int s0 = w, s1 = w + 8;
    const int stg_swz = ((lane & 3) * 16) ^ ((lane >> 5) << 5);
    uint32 goA[2][2], goB[2][2];
    #pragma unroll
    for (int h = 0; h < 2; ++h)
        #pragma unroll
        for (int ii = 0; ii < 2; ++ii) {
            int s = w + ii * 8;
            int rr = h * 128 + (s >> 1) * 16 + (lane >> 2);
            int kb = (s & 1) * 64 + stg_swz;
            goA[h][ii] = (uint32)(m0 + rr) * K2 + kb;
            goB[h][ii] = (uint32)(n0 + rr) * K2 + kb;
        }

    f32x4 acc[8][4] = {};
    short8 a[4][2], b0[2][2], b1[2][2];

    STG(1, 0, 0, 0); STG(0, 0, 0, 0); STG(1, 1, 0, 0); STG(0, 1, 0, 0);
    STG(1, 0, 1, 1); STG(0, 0, 1, 1);
    asm volatile("s_waitcnt vmcnt(4)" ::: "memory");
    BAR2;

    for (int it = 0; it < NITER; ++it) {
        const int T1 = 2 * it + 1;
        const int TN = 2 * it + 2;
        const bool nl = (it < NITER - 1);
        LDA(0, 0); LDB(b0, 0, 0);
        STG(1, 1, 1, T1);
        BAR1; MM(0, 0, b0); BAR2;
        LDB(b1, 0, 1);
        STG(0, 1, 1, T1);
        BAR1; MM(0, 1, b1); BAR2;
        LDA(0, 1);
        if (nl) STG(1, 0, 0, TN);
        BAR1; MM(1, 1, b1); BAR2;
        if (nl) { STG(0, 0, 0, TN);
                  asm volatile("s_waitcnt vmcnt(4)" ::: "memory"); }
        else    { asm volatile("s_waitcnt vmcnt(0)" ::: "memory"); }
        BAR1; MM(1, 0, b0); BAR2;
        LDA(1, 0); LDB(b0, 1, 0);
        if (nl) STG(1, 1, 0, TN);
        BAR1; MM(0, 0, b0); BAR2;
        LDB(b1, 1, 1);
        if (nl) STG(0, 1, 0, TN);
        BAR1; MM(0, 1, b1); BAR2;
        LDA(1, 1);
        if (nl) STG(1, 0, 1, TN + 1);
        BAR1; MM(1, 1, b1); BAR2;
        if (nl) STG(0, 0, 1, TN + 1);
        asm volatile("s_waitcnt vmcnt(4)" ::: "memory");
        BAR1; MM(1, 0, b0); BAR2;
    }

    #pragma unroll
    for (int fm = 0; fm < 8; ++fm) {
        int mbase = m0 + wm * 128 + fm * 16 + g * 4;
        #pragma unroll
        for (int fn = 0; fn < 4; ++fn) {
            int n = n0 + wn * 64 + fn * 16 + c16;
            #pragma unroll
            for (int r = 0; r < 4; ++r) {
                int m = mbase + r;
                float val = acc[fm][fn][r];
                if (EPI == 0) {
                    int bb = m >> 11, s = m & (S_LEN - 1);
                    u16 bv = f2bf(val);
                    if (n < DIMC) {
                        int h = n >> 7, d = n & 127;
                        q_raw[(((size_t)bb * NH + h) * S_LEN + s) * HD + d] = bv;
                    } else if (n < DIMC + NKV * HD) {
                        int h = (n - DIMC) >> 7, d = n & 127;
                        k_raw[(((size_t)bb * NKV + h) * S_LEN + s) * HD + d] = bv;
                    } else {
                        int h = (n - DIMC - NKV * HD) >> 7, d = n & 127;
                        v_t[(((size_t)bb * NKV + h) * HD + d) * S_LEN + s] = bv;
                    }
                } else {
                    outf[(size_t)m * DIMC + n] = val;
                }
            }
        }
    }
}

// ---------------- RoPE (in-place; 1/sqrt(HD)*log2(e) folded into q) ----------------
__global__ void rope_kernel(u16* __restrict__ q, u16* __restrict__ k,
                            const float* __restrict__ cosr, const float* __restrict__ sinr) {
    const int NQ = BATCH * NH * S_LEN * 16;
    const int NK = BATCH * NKV * S_LEN * 16;
    int idx = blockIdx.x * 256 + threadIdx.x;
    u16* ptr; int s; float scale; int ci;
    if (idx < NQ) {
        int row = idx >> 4; s = row & (S_LEN - 1);
        ptr = q + (size_t)idx * 8; scale = 0.12751744f; ci = idx & 15;   // 1/sqrt(128)*log2(e)
    } else if (idx < NQ + NK) {
        int i2 = idx - NQ; int row = i2 >> 4; s = row & (S_LEN - 1);
        ptr = k + (size_t)i2 * 8; scale = 1.0f; ci = i2 & 15;
    } else return;
    int p0 = ci * 4;
    fvec4 c  = *(const fvec4*)&cosr[s * 64 + p0];
    fvec4 sn = *(const fvec4*)&sinr[s * 64 + p0];
    short8 v = *(const short8*)ptr;
    short8 o;
    #pragma unroll
    for (int p = 0; p < 4; ++p) {
        float re = bf2f((u16)v[2 * p]), im = bf2f((u16)v[2 * p + 1]);
        o[2 * p]     = (short)f2bf((re * c[p] - im * sn[p]) * scale);
        o[2 * p + 1] = (short)f2bf((re * sn[p] + im * c[p]) * scale);
    }
    *(short8*)ptr = o;
}

// ---------------- flash attention: 8-warp 32x32 swapped-QK^T (m214 structure) ----------------
// grid (S/256, NH, B), 512 thr = 8 warps; warp owns 32 q-rows; KV tile = 64.
// mfma_32x32x16(K, Q) -> lane holds P-row (q = lane&31); softmax in-register;
// P->bf16 A-frags via cvt_pk + permlane32_swap (T12); defer-max (T13).
#define KVB 64
#define THR2 11.0f

#define STAGE_KV(DB, KV0) do { \
    _Pragma("unroll") for (int i_ = 0; i_ < 2; ++i_) { \
        int c_ = w * 2 + i_; \
        int kr_ = c_ * 4 + (lane >> 4); \
        int kb_ = ((lane & 15) * 16) ^ ((kr_ & 7) << 4); \
        gload_lds16(&K[(size_t)((KV0) + kr_) * HD + (kb_ >> 1)], &kT[DB][c_ * 512]); \
        int vr_ = c_ * 8 + (lane >> 3); \
        int vb_ = ((lane & 7) * 16) ^ ((vr_ & 7) << 4); \
        gload_lds16(&V[(size_t)vr_ * S_LEN + (KV0) + (vb_ >> 1)], &vT[DB][c_ * 512]); \
    } } while(0)

// one k-slot (16 kv): exp2, psum, pack P A-frag (cvt_pk + 2 swaps), 4 PV MFMAs
#define PKSLOT(SREG, KS, KOFF) do { \
    float p0 = exp2_fast(SREG[(KOFF)+0] - m2), p1 = exp2_fast(SREG[(KOFF)+1] - m2); \
    float p2 = exp2_fast(SREG[(KOFF)+2] - m2), p3 = exp2_fast(SREG[(KOFF)+3] - m2); \
    float p4 = exp2_fast(SREG[(KOFF)+4] - m2), p5 = exp2_fast(SREG[(KOFF)+5] - m2); \
    float p6 = exp2_fast(SREG[(KOFF)+6] - m2), p7 = exp2_fast(SREG[(KOFF)+7] - m2); \
    psum += (p0+p1)+(p2+p3)+((p4+p5)+(p6+p7)); \
    unsigned a01 = cvtpk_bf16(p0,p1), a23 = cvtpk_bf16(p2,p3); \
    unsigned b01 = cvtpk_bf16(p4,p5), b23 = cvtpk_bf16(p6,p7); \
    pl32swap(a01, b01); pl32swap(a23, b23); \
    union { short8 s8; unsigned u[4]; } pu; \
    pu.u[0] = a01; pu.u[1] = a23; pu.u[2] = b01; pu.u[3] = b23; \
    const int vcb_ = ((KS)*32 + hi*16) ^ ((l31 & 7) << 4); \
    _Pragma("unroll") for (int dt_ = 0; dt_ < 4; ++dt_) { \
        short8 vb = *(const short8*)((const char*)vbuf + (dt_*32 + l31)*128 + vcb_); \
        o_acc[dt_] = __builtin_amdgcn_mfma_f32_32x32x16_bf16(pu.s8, vb, o_acc[dt_], 0, 0, 0); \
    } } while(0)

__global__ __launch_bounds__(512, 2) void attn32(
    const u16* __restrict__ q_r, const u16* __restrict__ k_r,
    const u16* __restrict__ v_t, u16* __restrict__ att)
{
    __shared__ u16 kT[2][KVB * HD];        // 2 x 16 KB
    __shared__ u16 vT[2][HD * KVB];        // 2 x 16 KB
    __shared__ float aT[8][32];            // alpha / 1/l redistribution scratch
    const int qt = blockIdx.x, h = blockIdx.y, b = blockIdx.z;
    const int hkv = h >> 2;                // N_REP = 4
    const int t = threadIdx.x, lane = t & 63, w = t >> 6;
    const int l31 = lane & 31, hi = lane >> 5;

    const u16* Q = q_r + (((size_t)b * NH + h) * S_LEN + qt * 256 + w * 32 + l31) * HD;
    const u16* K = k_r + ((size_t)b * NKV + hkv) * S_LEN * HD;
    const u16* V = v_t + ((size_t)b * NKV + hkv) * HD * S_LEN;

    // Q B-frags: lane owns q-row l31; qb[ks] = Q[q][ks*16 + hi*8 .. +7]
    short8 qb[8];
    #pragma unroll
    for (int ks = 0; ks < 8; ++ks)
        qb[ks] = *(const short8*)&Q[ks * 16 + hi * 8];

    float m2 = -3e38f, l_run = 0.f;
    f32x16 o_acc[4] = {};

    STAGE_KV(0, 0);
    __syncthreads();

    int buf = 0;
    for (int tt = 0; tt < S_LEN / KVB; ++tt) {
        if (tt < S_LEN / KVB - 1) STAGE_KV(buf ^ 1, (tt + 1) * KVB);
        const u16* kbuf = kT[buf];
        const u16* vbuf = vT[buf];

        // ---- S^T = K Q^T via mfma(K, Q): D[kv][q], lane col = q ----
        f32x16 sA = {}, sB = {};
        #pragma unroll
        for (int ks = 0; ks < 8; ++ks) {
            int cb = (ks * 32 + hi * 16) ^ ((l31 & 7) << 4);
            short8 ka0 = *(const short8*)((const char*)kbuf + l31 * 256 + cb);
            short8 ka1 = *(const short8*)((const char*)kbuf + (32 + l31) * 256 + cb);
            sA = __builtin_amdgcn_mfma_f32_32x32x16_bf16(ka0, qb[ks], sA, 0, 0, 0);
            sB = __builtin_amdgcn_mfma_f32_32x32x16_bf16(ka1, qb[ks], sB, 0, 0, 0);
        }

        // ---- row max: 31 in-lane fmax + one half-swap shfl ----
        float mx = sA[0];
        #pragma unroll
        for (int e = 1; e < 16; ++e) mx = fmaxf(mx, sA[e]);
        #pragma unroll
        for (int e = 0; e < 16; ++e) mx = fmaxf(mx, sB[e]);
        mx = fmaxf(mx, __shfl_xor(mx, 32));

        // ---- defer-max (T13): rescale only when max grows past THR2 ----
        if (__any(mx > m2 + THR2)) {
            float mnew = fmaxf(m2, mx);
            float al = exp2_fast(m2 - mnew);
            m2 = mnew;
            l_run *= al;
            if (hi == 0) aT[w][l31] = al;
            asm volatile("s_waitcnt lgkmcnt(0)" ::: "memory");
            __builtin_amdgcn_sched_barrier(0);
            f32x4 av0 = *(f32x4*)&aT[w][hi * 4];
            f32x4 av1 = *(f32x4*)&aT[w][8 + hi * 4];
            f32x4 av2 = *(f32x4*)&aT[w][16 + hi * 4];
            f32x4 av3 = *(f32x4*)&aT[w][24 + hi * 4];
            #pragma unroll
            for (int dt = 0; dt < 4; ++dt)
                #pragma unroll
                for (int e = 0; e < 4; ++e) {
                    o_acc[dt][e]      *= av0[e];
                    o_acc[dt][4 + e]  *= av1[e];
                    o_acc[dt][8 + e]  *= av2[e];
                    o_acc[dt][12 + e] *= av3[e];
                }
        }

        // ---- P = 2^(S-m2); pack A-frags in-register; PV ----
        float psum = 0.f;
        PKSLOT(sA, 0, 0);
        PKSLOT(sA, 1, 8);
        PKSLOT(sB, 2, 0);
        PKSLOT(sB, 3, 8);
        l_run += psum;

        __syncthreads();
        buf ^= 1;
    }

    // ---- epilogue: combine l halves, redistribute 1/l by q-reg, store ----
    float l_tot = l_run + __shfl_xor(l_run, 32);
    float rl = 1.f / l_tot;
    if (hi == 0) aT[w][l31] = rl;
    asm volatile("s_waitcnt lgkmcnt(0)" ::: "memory");
    __builtin_amdgcn_sched_barrier(0);
    f32x4 rv0 = *(f32x4*)&aT[w][hi * 4];
    f32x4 rv1 = *(f32x4*)&aT[w][8 + hi * 4];
    f32x4 rv2 = *(f32x4*)&aT[w][16 + hi * 4];
    f32x4 rv3 = *(f32x4*)&aT[w][24 + hi * 4];
    const size_t mbase = (size_t)b * S_LEN + qt * 256 + w * 32;
    #pragma unroll
    for (int dt = 0; dt < 4; ++dt) {
        int dcol = h * HD + dt * 32 + l31;
        #pragma unroll
        for (int e = 0; e < 4; ++e) {
            att[(mbase + 8 * 0 + 4 * hi + e) * DIMC + dcol] = f2bf(o_acc[dt][e]      * rv0[e]);
            att[(mbase + 8 * 1 + 4 * hi + e) * DIMC + dcol] = f2bf(o_acc[dt][4 + e]  * rv1[e]);
            att[(mbase + 8 * 2 + 4 * hi + e) * DIMC + dcol] = f2bf(o_acc[dt][8 + e]  * rv2[e]);
            att[(mbase + 8 * 3 + 4 * hi + e) * DIMC + dcol] = f2bf(o_acc[dt][12 + e] * rv3[e]);
        }
    }
}

// ---------------- launch ----------------
extern "C" void kernel_launch(void* const* d_in, const int* in_sizes, int n_in,
                              void* d_out, int out_size, void* d_ws, size_t ws_size,
                              hipStream_t stream) {
    const float* x    = (const float*)d_in[0];
    const float* wq   = (const float*)d_in[1];
    const float* wk   = (const float*)d_in[2];
    const float* wv   = (const float*)d_in[3];
    const float* wo   = (const float*)d_in[4];
    const float* cosr = (const float*)d_in[7];
    const float* sinr = (const float*)d_in[8];
    float* out = (float*)d_out;

    char* ws = (char*)d_ws;
    u16* x_bf   = (u16*)(ws);                       //  32 MB
    u16* wqkv_t = (u16*)(ws + 33554432);            //  48 MB
    u16* wo_t   = (u16*)(ws + 83886080);            //  32 MB
    u16* q_r    = (u16*)(ws + 117440512);           //  32 MB
    u16* k_r    = (u16*)(ws + 150994944);           //   8 MB
    u16* v_t    = (u16*)(ws + 159383552);           //   8 MB
    u16* att    = (u16*)(ws + 167772160);           //  32 MB

    cvt_f32_bf16<<<16384, 256, 0, stream>>>(x, x_bf, (M_TOT * DIMC) / 4);
    transpose_cvt<<<dim3(128, 128), 256, 0, stream>>>(wq, wqkv_t, DIMC, 4096);
    transpose_cvt<<<dim3(32, 128), 256, 0, stream>>>(wk, wqkv_t + (size_t)4096 * DIMC, DIMC, 1024);
    transpose_cvt<<<dim3(32, 128), 256, 0, stream>>>(wv, wqkv_t + (size_t)5120 * DIMC, DIMC, 1024);
    transpose_cvt<<<dim3(128, 128), 256, 0, stream>>>(wo, wo_t, 4096, DIMC);

    gemm256<0><<<dim3(N_QKV / 256, M_TOT / 256), 512, 0, stream>>>(
        x_bf, wqkv_t, q_r, k_r, v_t, nullptr, DIMC);

    rope_kernel<<<(BATCH * (NH + NKV) * S_LEN * 16) / 256, 256, 0, stream>>>(q_r, k_r, cosr, sinr);

    attn32<<<dim3(S_LEN / 256, NH, BATCH), 512, 0, stream>>>(q_r, k_r, v_t, att);

    gemm256<1><<<dim3(DIMC / 256, M_TOT / 256), 512, 0, stream>>>(
        att, wo_t, nullptr, nullptr, nullptr, out, DIMC);
}